// Round 17
// baseline (595.512 us; speedup 1.0000x reference)
//
#include <hip/hip_runtime.h>
#include <hip/hip_bf16.h>
#include <math.h>

#define HIDDEN 192
#define NBINS 10
#define PROJ 29          // 3*NBINS-1
#define TAILF 5.0f
#define NLAYERS 3
#define NB 64
#define NT 2048
#define TT 64
#define HALO 13
#define COLS (TT + 2*HALO)   // 90
#define HS 94                 // hb bf16 row stride (47 dwords, odd -> conflict-free cols)
#define NPAD 96               // GEMM N padded
#define YS 194                // Yt bf16 row stride (97 dwords, odd)
#define NBLK (NT/(2*TT))      // 16 blocks per batch row (2 tiles per block)
#define NTB 32                // part entries per batch row
#define LN_EPS 1e-5f
#define MIN_BIN 1e-3f
#define MIN_DERF 1e-3f
#define INV_SQRTF 0.07216878364870323f   // 1/sqrt(192)
#define THREADS 1024
#define NWAVES 16

// LDS layout: shorts [hb0][hb1][yt0][yt1], then f32 [mk0][mk1][lnpp]
#define HB_SHORTS (HIDDEN*HS)                 // 18048
#define YT_SHORTS (NPAD*YS)                   // 18624
#define OFF_F32 ((2*HB_SHORTS + 2*YT_SHORTS)/2)   // dword index 36672
#define N_LNP (NLAYERS*2*HIDDEN)              // 1152 packed (g,b) dwords
#define SMEM_FLOATS (OFF_F32 + 2*COLS + N_LNP)    // 38004 dwords = 152016 B

#define WS_PART_BYTES 16384
#define WPW_ELEMS (NLAYERS*HIDDEN*HIDDEN)     // 110592
#define WPJ_ELEMS (32*HIDDEN)                 // 6144 (rows 29..31 zero)
#define WBF_TOTAL (WPW_ELEMS + WPJ_ELEMS)

typedef __attribute__((ext_vector_type(8))) short bf16x8;
typedef __attribute__((ext_vector_type(4))) float f32x4;

__device__ __forceinline__ unsigned short f2bf(float f) {
    __hip_bfloat16 h = __float2bfloat16(f);
    return __builtin_bit_cast(unsigned short, h);
}
__device__ __forceinline__ unsigned packbf(float lo, float hi_) {
    return (unsigned)f2bf(lo) | ((unsigned)f2bf(hi_) << 16);
}
__device__ __forceinline__ float bf2f_lo(unsigned u) {
    union { unsigned u; float f; } c; c.u = u << 16; return c.f;
}
__device__ __forceinline__ float bf2f_hi(unsigned u) {
    union { unsigned u; float f; } c; c.u = u & 0xffff0000u; return c.f;
}
__device__ __forceinline__ float bfs(unsigned short s) {
    union { unsigned u; float f; } c; c.u = ((unsigned)s) << 16; return c.f;
}

// exact GELU via A&S 7.1.26 rational erf (|err| < 1.5e-7), hw rcp/exp2
__device__ __forceinline__ float gelu_fast(float x) {
    const float az = fabsf(x) * 0.7071067811865476f;
    const float t  = __builtin_amdgcn_rcpf(fmaf(0.3275911f, az, 1.0f));
    float p = fmaf(1.061405429f, t, -1.453152027f);
    p = fmaf(p, t, 1.421413741f);
    p = fmaf(p, t, -0.284496736f);
    p = fmaf(p, t, 0.254829592f);
    p = p * t;
    const float e  = __builtin_amdgcn_exp2f(az*az*(-1.4426950408889634f));
    const float er = fmaf(-p, e, 1.0f);            // erf(|x|/sqrt2)
    const float se = (x >= 0.0f) ? er : -er;
    return 0.5f * x * (1.0f + se);
}
__device__ __forceinline__ float softplus_f(float x) {
    return (x > 20.0f) ? x : log1pf(expf(x));
}
__device__ __forceinline__ float wave_sum(float v) {
    #pragma unroll
    for (int o = 32; o > 0; o >>= 1) v += __shfl_xor(v, o, 64);
    return v;
}

// FUSED depthwise conv + LN + GELU for one column (8 lanes/col, 24 ch/lane).
// Conv results held in registers; one Yt write, no intermediate round-trip.
__device__ __forceinline__ void dw_ln1(const unsigned short* hbU, unsigned short* ytU,
                                       const float* dwwL, const float* dwbL,
                                       const unsigned* gb, int col, int q, int dil) {
    const int c0 = q * 24;
    float v[24];
    float s = 0.0f, ss = 0.0f;
    #pragma unroll
    for (int i = 0; i < 24; ++i) {
        const int c = c0 + i;
        const unsigned short* hrow = hbU + c*HS;
        const float w0 = dwwL[c*3], w1 = dwwL[c*3+1], w2 = dwwL[c*3+2];
        float r = dwbL[c] + w0*bfs(hrow[col-dil])
                          + w1*bfs(hrow[col    ])
                          + w2*bfs(hrow[col+dil]);
        v[i] = r; s += r; ss += r*r;
    }
    s  += __shfl_xor(s, 1, 64);  s  += __shfl_xor(s, 2, 64);  s  += __shfl_xor(s, 4, 64);
    ss += __shfl_xor(ss, 1, 64); ss += __shfl_xor(ss, 2, 64); ss += __shfl_xor(ss, 4, 64);
    const float mu  = s * (1.0f/HIDDEN);
    const float var = fmaxf(ss * (1.0f/HIDDEN) - mu*mu, 0.0f);
    const float rs  = rsqrtf(var + LN_EPS);
    unsigned* wp = (unsigned*)(ytU + col*YS + c0);
    #pragma unroll
    for (int i = 0; i < 12; ++i) {
        unsigned gb0 = gb[c0 + 2*i], gb1 = gb[c0 + 2*i + 1];
        float r0 = gelu_fast((v[2*i]   - mu)*rs*bf2f_lo(gb0) + bf2f_hi(gb0));
        float r1 = gelu_fast((v[2*i+1] - mu)*rs*bf2f_lo(gb1) + bf2f_hi(gb1));
        wp[i] = packbf(r0, r1);
    }
}

// LN2 + GELU + residual-add into pre-masked hb (8 lanes/col, 24 ch/lane).
// TWO-PASS over the LDS row (live regs ~15, spill-proof).
__device__ __forceinline__ void ln2_pass(const unsigned short* ytU, unsigned short* hbU,
                                         const unsigned* gb, const float* mkU,
                                         int col, int q, int jlo, int jhi) {
    if (col < jlo || col >= jhi) return;
    const int c0 = q * 24;
    const unsigned* rp = (const unsigned*)(ytU + col * YS + c0);
    float s = 0.0f, ss = 0.0f;
    #pragma unroll
    for (int i = 0; i < 12; ++i) {
        unsigned u = rp[i];
        float a = bf2f_lo(u), c = bf2f_hi(u);
        s += a + c; ss += a*a + c*c;
    }
    s  += __shfl_xor(s, 1, 64);  s  += __shfl_xor(s, 2, 64);  s  += __shfl_xor(s, 4, 64);
    ss += __shfl_xor(ss, 1, 64); ss += __shfl_xor(ss, 2, 64); ss += __shfl_xor(ss, 4, 64);
    const float mu  = s * (1.0f/HIDDEN);
    const float var = fmaxf(ss * (1.0f/HIDDEN) - mu*mu, 0.0f);
    const float rs  = rsqrtf(var + LN_EPS);
    const float mkv = mkU[col];
    #pragma unroll
    for (int i = 0; i < 12; ++i) {
        unsigned u = rp[i];
        unsigned gb0 = gb[c0 + 2*i], gb1 = gb[c0 + 2*i + 1];
        float r0 = gelu_fast((bf2f_lo(u) - mu)*rs*bf2f_lo(gb0) + bf2f_hi(gb0)) * mkv;
        float r1 = gelu_fast((bf2f_hi(u) - mu)*rs*bf2f_lo(gb1) + bf2f_hi(gb1)) * mkv;
        const int i0 = (c0 + 2*i)*HS + col;
        const int i1 = (c0 + 2*i + 1)*HS + col;
        hbU[i0] = f2bf(bfs(hbU[i0]) + r0);
        hbU[i1] = f2bf(bfs(hbU[i1]) + r1);
    }
}

__global__ void wconv_kernel(const float* __restrict__ pww, const float* __restrict__ pjw,
                             unsigned short* __restrict__ wbf) {
    int i = blockIdx.x * 1024 + threadIdx.x;
    if (i < WPW_ELEMS) {
        wbf[i] = f2bf(pww[i]);
    } else if (i < WBF_TOTAL) {
        int j = i - WPW_ELEMS;
        wbf[i] = (j < PROJ*HIDDEN) ? f2bf(pjw[j]) : (unsigned short)0;
    }
}

// PREW templated (dead fp32 fallback only in <0>). Extern shared + SetAttribute
// (R13 configuration). GEMM = R13's register-slim 3x3 (benign spills, fastest).
template <int PREW>
__global__ __launch_bounds__(THREADS, 4) void vits_fused(
    const float* __restrict__ inputs, const float* __restrict__ pmask,
    const float* __restrict__ cpw, const float* __restrict__ cpb,
    const float* __restrict__ dww, const float* __restrict__ dwb,
    const float* __restrict__ pww, const float* __restrict__ pwb,
    const float* __restrict__ g1, const float* __restrict__ b1,
    const float* __restrict__ g2, const float* __restrict__ b2,
    const float* __restrict__ pjw, const float* __restrict__ pjb,
    float* __restrict__ out, float* __restrict__ part,
    const unsigned short* __restrict__ wbf)
{
    extern __shared__ float sm[];
    unsigned short* hb0 = (unsigned short*)sm;
    unsigned short* hb1 = hb0 + HB_SHORTS;
    unsigned short* yt0 = hb1 + HB_SHORTS;
    unsigned short* yt1 = yt0 + YT_SHORTS;
    float* mk0 = sm + OFF_F32;
    float* mk1 = mk0 + COLS;
    unsigned* lnpp = (unsigned*)(mk1 + COLS);   // [L][{ln1,ln2}][192] packed (g,b)

    const int tid = threadIdx.x;
    const int lane = tid & 63;
    const int wid = tid >> 6;
    const int wu  = __builtin_amdgcn_readfirstlane(wid);
    const int b   = blockIdx.x / NBLK;
    const int tbb = blockIdx.x % NBLK;

    // ---- stage packed LN params + mask tiles ----
    for (int i = tid; i < N_LNP; i += THREADS) {
        const int L = i / (2*HIDDEN);
        const int r = i - L*2*HIDDEN;
        const int which = r / HIDDEN;
        const int c = r - which*HIDDEN;
        const float* gp = which ? g2 : g1;
        const float* bp = which ? b2 : b1;
        lnpp[i] = packbf(gp[L*HIDDEN + c], bp[L*HIDDEN + c]);
    }
    for (int i = tid; i < 2*COLS; i += THREADS) {
        const int u = i / COLS, j = i - u*COLS;
        const int t = (tbb*2 + u)*TT - HALO + j;
        const bool in = (t >= 0) && (t < NT);
        (u ? mk1 : mk0)[j] = in ? pmask[(size_t)b*NT + t] : 0.0f;
    }
    __syncthreads();

    // ---- conv_pre: hm = (cpw*fv + cpb) * mask (pre-masked residual stream) ----
    #pragma unroll
    for (int u = 0; u < 2; ++u) {
        unsigned short* hbU = u ? hb1 : hb0;
        const float* mkU = u ? mk1 : mk0;
        const int t0u = (tbb*2 + u)*TT - HALO;
        float fA = 0.0f, fB = 0.0f;
        { int t = t0u + lane; if (t >= 0 && t < NT) fA = inputs[(size_t)b*2*NT + t]; }
        { int t = t0u + 64 + lane; if (lane + 64 < COLS && t >= 0 && t < NT) fB = inputs[(size_t)b*2*NT + t]; }
        const float mA = mkU[lane];
        const float mB = (lane + 64 < COLS) ? mkU[lane + 64] : 0.0f;
        for (int c = wu; c < HIDDEN; c += NWAVES) {
            const float wv = cpw[c], bv = cpb[c];
            hbU[c*HS + lane] = f2bf((wv*fA + bv)*mA);
            if (lane + 64 < COLS) hbU[c*HS + lane + 64] = f2bf((wv*fB + bv)*mB);
        }
    }
    __syncthreads();

    const int dils[NLAYERS]  = {1, 3, 9};
    const int mouts[NLAYERS] = {1, 4, 13};

    const int l15 = lane & 15, hi = lane >> 4;
    const int g_u = wu >> 3;
    const int mgrp = wu & 3;
    const int ngrp = (wu >> 2) & 1;

    // LN slot mapping (8 lanes/col)
    const int slot = tid >> 3, q8 = tid & 7;
    const int lnA_u = (slot >= 96);
    const int lnA_col = lnA_u ? (slot - 96) : slot;

    for (int L = 0; L < NLAYERS; ++L) {
        const int dil = dils[L];
        const int jlo = mouts[L], jhi = COLS - mouts[L];
        const int nc = jhi - jlo;          // 88 / 82 / 64

        // ---- FUSED depthwise + LN1 + GELU -> Yt; zero dead rows ----
        {
            const float* dwwL = dww + (size_t)L*HIDDEN*3;
            const float* dwbL = dwb + (size_t)L*HIDDEN;
            const unsigned* gb = lnpp + (L*2+0)*HIDDEN;
            // call A: 64 cols per tile (nc >= 64 always)
            {
                const int u = slot >> 6;
                dw_ln1(u ? hb1 : hb0, u ? yt1 : yt0, dwwL, dwbL, gb,
                       jlo + (slot & 63), q8, dil);
            }
            // call B: remaining cols (24/18/0 per tile)
            const int rem = nc - 64;
            if (rem > 0 && slot < 2*rem) {
                const int u = (slot >= rem) ? 1 : 0;
                dw_ln1(u ? hb1 : hb0, u ? yt1 : yt0, dwwL, dwbL, gb,
                       jlo + 64 + (slot - u*rem), q8, dil);
            }
            // zero dead Yt rows [0,jlo) and [jhi,96) for both tiles
            const int ndead = jlo + (96 - jhi);
            for (int idx = tid; idx < 2*ndead*97; idx += THREADS) {
                const int u = idx / (ndead*97);
                int r = idx - u*(ndead*97);
                const int k = r / 97, d = r - k*97;
                const int row = (k < jlo) ? k : (jhi + (k - jlo));
                ((unsigned*)(u ? yt1 : yt0))[row*97 + d] = 0u;
            }
        }
        __syncthreads();

        // ---- pointwise 192x192 GEMM via MFMA: wave = (tile, 48x48 block) ----
        // Register-slim: fresh B (4x b32 LDS) and fresh A per MFMA. (R13)
        {
            unsigned short* ytU = g_u ? yt1 : yt0;
            f32x4 acc[3][3];
            #pragma unroll
            for (int mt = 0; mt < 3; ++mt)
                #pragma unroll
                for (int nt = 0; nt < 3; ++nt)
                    acc[mt][nt] = (f32x4){0.0f, 0.0f, 0.0f, 0.0f};

            if constexpr (PREW) {
                const unsigned short* wbl = wbf + (size_t)L*HIDDEN*HIDDEN;
                #pragma unroll
                for (int nt = 0; nt < 3; ++nt) {
                    const unsigned short* yr = ytU + (ngrp*48 + nt*16 + l15)*YS + hi*8;
                    #pragma unroll
                    for (int mt = 0; mt < 3; ++mt) {
                        const unsigned short* wr = wbl + (size_t)(mgrp*48 + mt*16 + l15)*HIDDEN + hi*8;
                        #pragma unroll
                        for (int ks = 0; ks < 6; ++ks) {
                            const unsigned* p = (const unsigned*)(yr + ks*32);
                            union { unsigned uu[4]; bf16x8 v; } cv;
                            cv.uu[0] = p[0]; cv.uu[1] = p[1]; cv.uu[2] = p[2]; cv.uu[3] = p[3];
                            bf16x8 a = *(const bf16x8*)(wr + ks*32);
                            acc[mt][nt] = __builtin_amdgcn_mfma_f32_16x16x32_bf16(a, cv.v, acc[mt][nt], 0, 0, 0);
                        }
                    }
                }
            } else {
                const float* wlayer = pww + (size_t)L*HIDDEN*HIDDEN;
                #pragma unroll
                for (int nt = 0; nt < 3; ++nt) {
                    const unsigned short* yr = ytU + (ngrp*48 + nt*16 + l15)*YS + hi*8;
                    #pragma unroll
                    for (int mt = 0; mt < 3; ++mt) {
                        const float* wr = wlayer + (size_t)(mgrp*48 + mt*16 + l15)*HIDDEN + hi*8;
                        #pragma unroll
                        for (int ks = 0; ks < 6; ++ks) {
                            const unsigned* p = (const unsigned*)(yr + ks*32);
                            union { unsigned uu[4]; bf16x8 v; } cv;
                            cv.uu[0] = p[0]; cv.uu[1] = p[1]; cv.uu[2] = p[2]; cv.uu[3] = p[3];
                            float4 a0 = *(const float4*)(wr + ks*32);
                            float4 a1 = *(const float4*)(wr + ks*32 + 4);
                            bf16x8 a;
                            a[0] = (short)f2bf(a0.x); a[1] = (short)f2bf(a0.y);
                            a[2] = (short)f2bf(a0.z); a[3] = (short)f2bf(a0.w);
                            a[4] = (short)f2bf(a1.x); a[5] = (short)f2bf(a1.y);
                            a[6] = (short)f2bf(a1.z); a[7] = (short)f2bf(a1.w);
                            acc[mt][nt] = __builtin_amdgcn_mfma_f32_16x16x32_bf16(a, cv.v, acc[mt][nt], 0, 0, 0);
                        }
                    }
                }
            }
            __syncthreads();   // all Yt reads complete before overwrite

            // bias + write z back over Yt (bf16)
            #pragma unroll
            for (int mt = 0; mt < 3; ++mt) {
                const int mrow = mgrp*48 + mt*16 + hi*4;
                float4 bias = *(const float4*)(pwb + L*HIDDEN + mrow);
                unsigned short* ytW = g_u ? yt1 : yt0;
                #pragma unroll
                for (int nt = 0; nt < 3; ++nt) {
                    const int n = ngrp*48 + nt*16 + l15;
                    unsigned* zr = (unsigned*)(ytW + n*YS + mrow);
                    f32x4 v = acc[mt][nt];
                    zr[0] = packbf(v[0] + bias.x, v[1] + bias.y);
                    zr[1] = packbf(v[2] + bias.z, v[3] + bias.w);
                }
            }
        }
        __syncthreads();

        // ---- LN2 + GELU + residual (times mask) into hm (bf16) ----
        {
            const unsigned* gb = lnpp + (L*2+1)*HIDDEN;
            ln2_pass(lnA_u ? yt1 : yt0, lnA_u ? hb1 : hb0, gb, lnA_u ? mk1 : mk0,
                     lnA_col, q8, jlo, jhi);
            if (slot < 64)
                ln2_pass(yt1, hb1, gb, mk1, slot + 32, q8, jlo, jhi);
        }
        __syncthreads();
    }

    // ---- projection: p[o][j] = (proj_w @ hm + proj_b) * mask ----
    if constexpr (PREW) {
        const unsigned short* wpj = wbf + WPW_ELEMS;
        const int p_u = wu >> 3;
        const int p_mt = (wu >> 2) & 1;
        const int p_nt = wu & 3;
        unsigned short* hbU = p_u ? hb1 : hb0;
        float* pbU = (float*)(p_u ? yt1 : yt0);
        const float* mkU = p_u ? mk1 : mk0;
        const int j = p_nt*16 + l15;
        const int jj = HALO + j;
        f32x4 pacc = (f32x4){0.0f, 0.0f, 0.0f, 0.0f};
        #pragma unroll
        for (int ks = 0; ks < 6; ++ks) {
            bf16x8 a = *(const bf16x8*)(wpj + (size_t)(p_mt*16 + l15)*HIDDEN + ks*32 + hi*8);
            bf16x8 bb;
            #pragma unroll
            for (int e = 0; e < 8; ++e)
                bb[e] = (short)hbU[(ks*32 + hi*8 + e)*HS + jj];
            pacc = __builtin_amdgcn_mfma_f32_16x16x32_bf16(a, bb, pacc, 0, 0, 0);
        }
        const float mkv = mkU[jj];
        #pragma unroll
        for (int r = 0; r < 4; ++r) {
            const int o = p_mt*16 + hi*4 + r;
            if (o < PROJ)
                pbU[j*33 + o] = (pacc[r] + pjb[o]) * mkv;
        }
    } else {
        #pragma unroll
        for (int u = 0; u < 2; ++u) {
            unsigned short* hbU = u ? hb1 : hb0;
            float* pbU = (float*)(u ? yt1 : yt0);
            const float* mkU = u ? mk1 : mk0;
            const int j = lane;
            const int jj = HALO + j;
            const float mkv = mkU[jj];
            #pragma unroll
            for (int k = 0; k < 2; ++k) {
                const int o = wu + 16*k;
                if (o < PROJ) {
                    const float* w = pjw + (size_t)o*HIDDEN;
                    float acc = 0.0f;
                    #pragma unroll 4
                    for (int c = 0; c < HIDDEN; ++c)
                        acc = fmaf(w[c], bfs(hbU[c*HS + jj]), acc);
                    pbU[j*33 + o] = (acc + pjb[o]) * mkv;
                }
            }
        }
    }
    __syncthreads();

    // ---- spline epilogue: waves 0,1 -> tiles 0,1; scratch over hb ----
    float ladm = 0.0f;
    if (tid < 2*TT) {
        const int u = tid >> 6, j = tid & 63;
        float* pbU = (float*)(u ? yt1 : yt0);
        float* sc  = (float*)(u ? hb1 : hb0);
        const float* mkU = u ? mk1 : mk0;
        const int t = (tbb*2 + u)*TT + j;
        float* S  = sc + j*57;
        float* cw = S;          // 11
        float* ch = S + 11;     // 11
        float* wd = S + 22;     // 10
        float* ht = S + 32;     // 10
        float* dv = S + 42;     // 11

        const float x   = inputs[(size_t)b*2*NT + NT + t];
        const float fvv = inputs[(size_t)b*2*NT + t];
        const float mv  = mkU[HALO + j];

        {
            float uarr[NBINS]; float m = -1e30f;
            #pragma unroll
            for (int k = 0; k < NBINS; ++k) { uarr[k] = pbU[j*33 + k]*INV_SQRTF; m = fmaxf(m, uarr[k]); }
            float se = 0.0f;
            #pragma unroll
            for (int k = 0; k < NBINS; ++k) { uarr[k] = expf(uarr[k] - m); se += uarr[k]; }
            float inv = 1.0f/se, csum = 0.0f;
            cw[0] = -TAILF;
            #pragma unroll
            for (int k = 0; k < NBINS; ++k) {
                float wk = MIN_BIN + (1.0f - NBINS*MIN_BIN)*uarr[k]*inv;
                csum += wk;
                cw[k+1] = 2.0f*TAILF*csum - TAILF;
            }
            cw[NBINS] = TAILF;
            #pragma unroll
            for (int k = 0; k < NBINS; ++k) wd[k] = cw[k+1] - cw[k];
        }
        {
            float uarr[NBINS]; float m = -1e30f;
            #pragma unroll
            for (int k = 0; k < NBINS; ++k) { uarr[k] = pbU[j*33 + 10 + k]*INV_SQRTF; m = fmaxf(m, uarr[k]); }
            float se = 0.0f;
            #pragma unroll
            for (int k = 0; k < NBINS; ++k) { uarr[k] = expf(uarr[k] - m); se += uarr[k]; }
            float inv = 1.0f/se, csum = 0.0f;
            ch[0] = -TAILF;
            #pragma unroll
            for (int k = 0; k < NBINS; ++k) {
                float wk = MIN_BIN + (1.0f - NBINS*MIN_BIN)*uarr[k]*inv;
                csum += wk;
                ch[k+1] = 2.0f*TAILF*csum - TAILF;
            }
            ch[NBINS] = TAILF;
            #pragma unroll
            for (int k = 0; k < NBINS; ++k) ht[k] = ch[k+1] - ch[k];
        }
        {
            const float cpad = logf(expf(1.0f - MIN_DERF) - 1.0f);
            float edge = MIN_DERF + softplus_f(cpad);
            dv[0] = edge;
            #pragma unroll
            for (int k = 0; k < NBINS-1; ++k) dv[k+1] = MIN_DERF + softplus_f(pbU[j*33 + 2*NBINS + k]);
            dv[NBINS] = edge;
        }

        const float xi = fminf(fmaxf(x, -TAILF), TAILF);
        int cnt = 0;
        #pragma unroll
        for (int k = 0; k <= NBINS; ++k) {
            float bl = cw[k] + ((k == NBINS) ? 1e-6f : 0.0f);
            cnt += (xi >= bl) ? 1 : 0;
        }
        int bi = cnt - 1;
        bi = (bi < 0) ? 0 : ((bi > NBINS-1) ? NBINS-1 : bi);

        const float in_cw = cw[bi], in_w = wd[bi];
        const float in_ch = ch[bi], in_h = ht[bi];
        const float in_d  = ht[bi]/wd[bi];
        const float dA = dv[bi], dB = dv[bi+1];
        const float i1 = dA + dB - 2.0f*in_d;
        const float th = (xi - in_cw)/in_w;
        const float t1m = th*(1.0f - th);
        const float den = in_d + i1*t1m;
        const float outv = in_ch + in_h*(in_d*th*th + dA*t1m)/den;
        const float omt = 1.0f - th;
        const float dnum = in_d*in_d*(dB*th*th + 2.0f*in_d*t1m + dA*omt*omt);
        const float lad = logf(dnum) - 2.0f*logf(den);

        const bool inside = (x >= -TAILF) && (x <= TAILF);
        const float sec  = inside ? outv : x;
        ladm = (inside ? lad : 0.0f) * mv;

        out[(size_t)b*2*NT + t]      = fvv*mv;
        out[(size_t)b*2*NT + NT + t] = sec*mv;
    }
    if (tid < 128) {
        float tot = wave_sum(ladm);
        if (lane == 0) part[b*NTB + tbb*2 + (tid >> 6)] = tot;
    }
}

__global__ void ld_reduce(const float* __restrict__ part, float* __restrict__ ld) {
    int b = threadIdx.x;
    if (b < NB) {
        float s = 0.0f;
        for (int k = 0; k < NTB; ++k) s += part[b*NTB + k];
        ld[b] = s;
    }
}

extern "C" void kernel_launch(void* const* d_in, const int* in_sizes, int n_in,
                              void* d_out, int out_size, void* d_ws, size_t ws_size,
                              hipStream_t stream) {
    const float* inputs = (const float*)d_in[0];
    const float* pmask  = (const float*)d_in[1];
    const float* cpw    = (const float*)d_in[2];
    const float* cpb    = (const float*)d_in[3];
    const float* dww    = (const float*)d_in[4];
    const float* dwb    = (const float*)d_in[5];
    const float* pww    = (const float*)d_in[6];
    const float* pwb    = (const float*)d_in[7];
    const float* g1     = (const float*)d_in[8];
    const float* b1     = (const float*)d_in[9];
    const float* g2     = (const float*)d_in[10];
    const float* b2     = (const float*)d_in[11];
    const float* pjw    = (const float*)d_in[12];
    const float* pjb    = (const float*)d_in[13];
    float* out  = (float*)d_out;
    float* part = (float*)d_ws;

    const size_t need = WS_PART_BYTES + (size_t)WBF_TOTAL*2;
    const int preW = (ws_size >= need) ? 1 : 0;
    unsigned short* wbf = (unsigned short*)((char*)d_ws + WS_PART_BYTES);

    const size_t smem = (size_t)SMEM_FLOATS * sizeof(float);
    if (preW) {
        wconv_kernel<<<(WBF_TOTAL + 1023)/1024, 1024, 0, stream>>>(pww, pjw, wbf);
        hipFuncSetAttribute(reinterpret_cast<const void*>(&vits_fused<1>),
                            hipFuncAttributeMaxDynamicSharedMemorySize, (int)smem);
        vits_fused<1><<<NB*NBLK, THREADS, smem, stream>>>(inputs, pmask, cpw, cpb, dww, dwb,
                                                          pww, pwb, g1, b1, g2, b2, pjw, pjb,
                                                          out, part, wbf);
    } else {
        hipFuncSetAttribute(reinterpret_cast<const void*>(&vits_fused<0>),
                            hipFuncAttributeMaxDynamicSharedMemorySize, (int)smem);
        vits_fused<0><<<NB*NBLK, THREADS, smem, stream>>>(inputs, pmask, cpw, cpb, dww, dwb,
                                                          pww, pwb, g1, b1, g2, b2, pjw, pjb,
                                                          out, part, wbf);
    }
    ld_reduce<<<1, 64, 0, stream>>>(part, out + (size_t)NB*2*NT);
}

// Round 18
// 432.872 us; speedup vs baseline: 1.3757x; 1.3757x over previous
//
#include <hip/hip_runtime.h>
#include <hip/hip_bf16.h>
#include <math.h>

#define HIDDEN 192
#define NBINS 10
#define PROJ 29          // 3*NBINS-1
#define TAILF 5.0f
#define NLAYERS 3
#define NB 64
#define NT 2048
#define TT 64
#define HALO 13
#define COLS (TT + 2*HALO)   // 90
#define HS 94                 // hb bf16 row stride (47 dwords, odd -> conflict-free cols)
#define NPAD 96               // GEMM N padded
#define YS 194                // Yt bf16 row stride (97 dwords, odd)
#define NBLK (NT/(2*TT))      // 16 blocks per batch row (2 tiles per block)
#define NTB 32                // part entries per batch row
#define LN_EPS 1e-5f
#define MIN_BIN 1e-3f
#define MIN_DERF 1e-3f
#define INV_SQRTF 0.07216878364870323f   // 1/sqrt(192)
#define THREADS 1024
#define NWAVES 16

// LDS layout: shorts [hb0][hb1][yt0][yt1], then f32 [mk0][mk1][lnpp]
#define HB_SHORTS (HIDDEN*HS)                 // 18048
#define YT_SHORTS (NPAD*YS)                   // 18624
#define OFF_F32 ((2*HB_SHORTS + 2*YT_SHORTS)/2)   // dword index 36672
#define N_LNP (NLAYERS*2*HIDDEN)              // 1152 packed (g,b) dwords
#define SMEM_FLOATS (OFF_F32 + 2*COLS + N_LNP)    // 38004 dwords = 152016 B

#define WS_PART_BYTES 16384
#define WPW_ELEMS (NLAYERS*HIDDEN*HIDDEN)     // 110592
#define WPJ_ELEMS (32*HIDDEN)                 // 6144 (rows 29..31 zero)
#define WBF_TOTAL (WPW_ELEMS + WPJ_ELEMS)

typedef __attribute__((ext_vector_type(8))) short bf16x8;
typedef __attribute__((ext_vector_type(4))) float f32x4;

__device__ __forceinline__ unsigned short f2bf(float f) {
    __hip_bfloat16 h = __float2bfloat16(f);
    return __builtin_bit_cast(unsigned short, h);
}
__device__ __forceinline__ unsigned packbf(float lo, float hi_) {
    return (unsigned)f2bf(lo) | ((unsigned)f2bf(hi_) << 16);
}
__device__ __forceinline__ float bf2f_lo(unsigned u) {
    union { unsigned u; float f; } c; c.u = u << 16; return c.f;
}
__device__ __forceinline__ float bf2f_hi(unsigned u) {
    union { unsigned u; float f; } c; c.u = u & 0xffff0000u; return c.f;
}
__device__ __forceinline__ float bfs(unsigned short s) {
    union { unsigned u; float f; } c; c.u = ((unsigned)s) << 16; return c.f;
}

// exact GELU via A&S 7.1.26 rational erf (|err| < 1.5e-7), hw rcp/exp2
__device__ __forceinline__ float gelu_fast(float x) {
    const float az = fabsf(x) * 0.7071067811865476f;
    const float t  = __builtin_amdgcn_rcpf(fmaf(0.3275911f, az, 1.0f));
    float p = fmaf(1.061405429f, t, -1.453152027f);
    p = fmaf(p, t, 1.421413741f);
    p = fmaf(p, t, -0.284496736f);
    p = fmaf(p, t, 0.254829592f);
    p = p * t;
    const float e  = __builtin_amdgcn_exp2f(az*az*(-1.4426950408889634f));
    const float er = fmaf(-p, e, 1.0f);            // erf(|x|/sqrt2)
    const float se = (x >= 0.0f) ? er : -er;
    return 0.5f * x * (1.0f + se);
}
__device__ __forceinline__ float softplus_f(float x) {
    return (x > 20.0f) ? x : log1pf(expf(x));
}
__device__ __forceinline__ float wave_sum(float v) {
    #pragma unroll
    for (int o = 32; o > 0; o >>= 1) v += __shfl_xor(v, o, 64);
    return v;
}

// LN over channels for one column (8 lanes/col, 24 ch/lane) + GELU.
// TWO-PASS over the LDS row (live regs ~15, spill-proof).
__device__ __forceinline__ void ln_pass(unsigned short* ytU, unsigned short* hbU,
                                        const unsigned* gb, const float* mkU,
                                        int col, int q, int jlo, int jhi, bool toYt) {
    const int c0 = q * 24;
    unsigned short* row = ytU + col * YS;
    unsigned* wp = (unsigned*)(row + c0);
    if (col < jlo || col >= jhi) {
        if (toYt) {
            #pragma unroll
            for (int i = 0; i < 12; ++i) wp[i] = 0u;
        }
        return;
    }
    const unsigned* rp = (const unsigned*)(row + c0);
    float s = 0.0f, ss = 0.0f;
    #pragma unroll
    for (int i = 0; i < 12; ++i) {
        unsigned u = rp[i];
        float a = bf2f_lo(u), c = bf2f_hi(u);
        s += a + c; ss += a*a + c*c;
    }
    s  += __shfl_xor(s, 1, 64);  s  += __shfl_xor(s, 2, 64);  s  += __shfl_xor(s, 4, 64);
    ss += __shfl_xor(ss, 1, 64); ss += __shfl_xor(ss, 2, 64); ss += __shfl_xor(ss, 4, 64);
    const float mu  = s * (1.0f/HIDDEN);
    const float var = fmaxf(ss * (1.0f/HIDDEN) - mu*mu, 0.0f);
    const float rs  = rsqrtf(var + LN_EPS);

    if (toYt) {
        #pragma unroll
        for (int i = 0; i < 12; ++i) {
            unsigned u = rp[i];
            unsigned gb0 = gb[c0 + 2*i], gb1 = gb[c0 + 2*i + 1];
            float r0 = gelu_fast((bf2f_lo(u) - mu)*rs*bf2f_lo(gb0) + bf2f_hi(gb0));
            float r1 = gelu_fast((bf2f_hi(u) - mu)*rs*bf2f_lo(gb1) + bf2f_hi(gb1));
            wp[i] = packbf(r0, r1);
        }
    } else {
        const float mkv = mkU[col];
        #pragma unroll
        for (int i = 0; i < 12; ++i) {
            unsigned u = rp[i];
            unsigned gb0 = gb[c0 + 2*i], gb1 = gb[c0 + 2*i + 1];
            float r0 = gelu_fast((bf2f_lo(u) - mu)*rs*bf2f_lo(gb0) + bf2f_hi(gb0)) * mkv;
            float r1 = gelu_fast((bf2f_hi(u) - mu)*rs*bf2f_lo(gb1) + bf2f_hi(gb1)) * mkv;
            const int i0 = (c0 + 2*i)*HS + col;
            const int i1 = (c0 + 2*i + 1)*HS + col;
            hbU[i0] = f2bf(bfs(hbU[i0]) + r0);
            hbU[i1] = f2bf(bfs(hbU[i1]) + r1);
        }
    }
}

__global__ void wconv_kernel(const float* __restrict__ pww, const float* __restrict__ pjw,
                             unsigned short* __restrict__ wbf) {
    int i = blockIdx.x * 1024 + threadIdx.x;
    if (i < WPW_ELEMS) {
        wbf[i] = f2bf(pww[i]);
    } else if (i < WBF_TOTAL) {
        int j = i - WPW_ELEMS;
        wbf[i] = (j < PROJ*HIDDEN) ? f2bf(pjw[j]) : (unsigned short)0;
    }
}

// PREW templated: the fp32-weight fallback lives ONLY in the <0> instantiation,
// so the <1> kernel's register allocation is not polluted by the dead branch.
template <int PREW>
__global__ __launch_bounds__(THREADS, 4) void vits_fused(
    const float* __restrict__ inputs, const float* __restrict__ pmask,
    const float* __restrict__ cpw, const float* __restrict__ cpb,
    const float* __restrict__ dww, const float* __restrict__ dwb,
    const float* __restrict__ pww, const float* __restrict__ pwb,
    const float* __restrict__ g1, const float* __restrict__ b1,
    const float* __restrict__ g2, const float* __restrict__ b2,
    const float* __restrict__ pjw, const float* __restrict__ pjb,
    float* __restrict__ out, float* __restrict__ part,
    const unsigned short* __restrict__ wbf)
{
    extern __shared__ float sm[];
    unsigned short* hb0 = (unsigned short*)sm;
    unsigned short* hb1 = hb0 + HB_SHORTS;
    unsigned short* yt0 = hb1 + HB_SHORTS;
    unsigned short* yt1 = yt0 + YT_SHORTS;
    float* mk0 = sm + OFF_F32;
    float* mk1 = mk0 + COLS;
    unsigned* lnpp = (unsigned*)(mk1 + COLS);   // [L][{ln1,ln2}][192] packed (g,b)

    const int tid = threadIdx.x;
    const int lane = tid & 63;
    const int wid = tid >> 6;
    const int wu  = __builtin_amdgcn_readfirstlane(wid);
    const int b   = blockIdx.x / NBLK;
    const int tbb = blockIdx.x % NBLK;

    // ---- stage packed LN params + mask tiles ----
    for (int i = tid; i < N_LNP; i += THREADS) {
        const int L = i / (2*HIDDEN);
        const int r = i - L*2*HIDDEN;
        const int which = r / HIDDEN;
        const int c = r - which*HIDDEN;
        const float* gp = which ? g2 : g1;
        const float* bp = which ? b2 : b1;
        lnpp[i] = packbf(gp[L*HIDDEN + c], bp[L*HIDDEN + c]);
    }
    for (int i = tid; i < 2*COLS; i += THREADS) {
        const int u = i / COLS, j = i - u*COLS;
        const int t = (tbb*2 + u)*TT - HALO + j;
        const bool in = (t >= 0) && (t < NT);
        (u ? mk1 : mk0)[j] = in ? pmask[(size_t)b*NT + t] : 0.0f;
    }
    __syncthreads();

    // ---- conv_pre: hm = (cpw*fv + cpb) * mask (pre-masked residual stream) ----
    #pragma unroll
    for (int u = 0; u < 2; ++u) {
        unsigned short* hbU = u ? hb1 : hb0;
        const float* mkU = u ? mk1 : mk0;
        const int t0u = (tbb*2 + u)*TT - HALO;
        float fA = 0.0f, fB = 0.0f;
        { int t = t0u + lane; if (t >= 0 && t < NT) fA = inputs[(size_t)b*2*NT + t]; }
        { int t = t0u + 64 + lane; if (lane + 64 < COLS && t >= 0 && t < NT) fB = inputs[(size_t)b*2*NT + t]; }
        const float mA = mkU[lane];
        const float mB = (lane + 64 < COLS) ? mkU[lane + 64] : 0.0f;
        for (int c = wu; c < HIDDEN; c += NWAVES) {
            const float wv = cpw[c], bv = cpb[c];
            hbU[c*HS + lane] = f2bf((wv*fA + bv)*mA);
            if (lane + 64 < COLS) hbU[c*HS + lane + 64] = f2bf((wv*fB + bv)*mB);
        }
    }
    __syncthreads();

    const int dils[NLAYERS]  = {1, 3, 9};
    const int mouts[NLAYERS] = {1, 4, 13};

    const int l15 = lane & 15, hi = lane >> 4;
    const int g_u = wu >> 3;
    const int mgrp = wu & 3;
    const int ngrp = (wu >> 2) & 1;

    // LN slot mapping (call A covers tile0 cols 0..95 + tile1 cols 0..31; call B tile1 cols 32..95)
    const int slot = tid >> 3, q8 = tid & 7;
    const int lnA_u = (slot >= 96);
    const int lnA_col = lnA_u ? (slot - 96) : slot;

    for (int L = 0; L < NLAYERS; ++L) {
        const int dil = dils[L];
        const int jlo = mouts[L], jhi = COLS - mouts[L];

        // ---- depthwise dilated conv + bias -> Yt (input pre-masked: no mk muls) ----
        #pragma unroll
        for (int u = 0; u < 2; ++u) {
            unsigned short* hbU = u ? hb1 : hb0;
            unsigned short* ytU = u ? yt1 : yt0;
            const int jA = jlo + lane;
            const int jB = jlo + 64 + lane;
            const bool actB = jB < jhi;
            for (int c = wu; c < HIDDEN; c += NWAVES) {
                const float* w = dww + ((size_t)L*HIDDEN + c)*3;
                const float w0 = w[0], w1 = w[1], w2 = w[2];
                const float bv = dwb[L*HIDDEN + c];
                const unsigned short* hrow = hbU + c*HS;
                float vA = bv + w0*bfs(hrow[jA-dil])
                              + w1*bfs(hrow[jA    ])
                              + w2*bfs(hrow[jA+dil]);
                ytU[jA*YS + c] = f2bf(vA);
                if (actB) {
                    float vB = bv + w0*bfs(hrow[jB-dil])
                                  + w1*bfs(hrow[jB    ])
                                  + w2*bfs(hrow[jB+dil]);
                    ytU[jB*YS + c] = f2bf(vB);
                }
            }
        }
        __syncthreads();

        // ---- LN1 + GELU in place on Yt (dead cols zeroed) ----
        {
            const unsigned* gb = lnpp + (L*2+0)*HIDDEN;
            ln_pass(lnA_u ? yt1 : yt0, lnA_u ? hb1 : hb0, gb, lnA_u ? mk1 : mk0,
                    lnA_col, q8, jlo, jhi, true);
            if (slot < 64)
                ln_pass(yt1, hb1, gb, mk1, slot + 32, q8, jlo, jhi, true);
        }
        __syncthreads();

        // ---- pointwise 192x192 GEMM via MFMA: wave = (tile, 48x48 block) ----
        // Register-slim: fresh B (4x b32 LDS) and fresh A per MFMA.
        {
            unsigned short* ytU = g_u ? yt1 : yt0;
            f32x4 acc[3][3];
            #pragma unroll
            for (int mt = 0; mt < 3; ++mt)
                #pragma unroll
                for (int nt = 0; nt < 3; ++nt)
                    acc[mt][nt] = (f32x4){0.0f, 0.0f, 0.0f, 0.0f};

            if constexpr (PREW) {
                const unsigned short* wbl = wbf + (size_t)L*HIDDEN*HIDDEN;
                #pragma unroll
                for (int nt = 0; nt < 3; ++nt) {
                    const unsigned short* yr = ytU + (ngrp*48 + nt*16 + l15)*YS + hi*8;
                    #pragma unroll
                    for (int mt = 0; mt < 3; ++mt) {
                        const unsigned short* wr = wbl + (size_t)(mgrp*48 + mt*16 + l15)*HIDDEN + hi*8;
                        #pragma unroll
                        for (int ks = 0; ks < 6; ++ks) {
                            const unsigned* p = (const unsigned*)(yr + ks*32);
                            union { unsigned uu[4]; bf16x8 v; } cv;
                            cv.uu[0] = p[0]; cv.uu[1] = p[1]; cv.uu[2] = p[2]; cv.uu[3] = p[3];
                            bf16x8 a = *(const bf16x8*)(wr + ks*32);
                            acc[mt][nt] = __builtin_amdgcn_mfma_f32_16x16x32_bf16(a, cv.v, acc[mt][nt], 0, 0, 0);
                        }
                    }
                }
            } else {
                const float* wlayer = pww + (size_t)L*HIDDEN*HIDDEN;
                #pragma unroll
                for (int nt = 0; nt < 3; ++nt) {
                    const unsigned short* yr = ytU + (ngrp*48 + nt*16 + l15)*YS + hi*8;
                    #pragma unroll
                    for (int mt = 0; mt < 3; ++mt) {
                        const float* wr = wlayer + (size_t)(mgrp*48 + mt*16 + l15)*HIDDEN + hi*8;
                        #pragma unroll
                        for (int ks = 0; ks < 6; ++ks) {
                            const unsigned* p = (const unsigned*)(yr + ks*32);
                            union { unsigned uu[4]; bf16x8 v; } cv;
                            cv.uu[0] = p[0]; cv.uu[1] = p[1]; cv.uu[2] = p[2]; cv.uu[3] = p[3];
                            float4 a0 = *(const float4*)(wr + ks*32);
                            float4 a1 = *(const float4*)(wr + ks*32 + 4);
                            bf16x8 a;
                            a[0] = (short)f2bf(a0.x); a[1] = (short)f2bf(a0.y);
                            a[2] = (short)f2bf(a0.z); a[3] = (short)f2bf(a0.w);
                            a[4] = (short)f2bf(a1.x); a[5] = (short)f2bf(a1.y);
                            a[6] = (short)f2bf(a1.z); a[7] = (short)f2bf(a1.w);
                            acc[mt][nt] = __builtin_amdgcn_mfma_f32_16x16x32_bf16(a, cv.v, acc[mt][nt], 0, 0, 0);
                        }
                    }
                }
            }
            __syncthreads();   // all Yt reads complete before overwrite

            // bias + write z back over Yt (bf16)
            #pragma unroll
            for (int mt = 0; mt < 3; ++mt) {
                const int mrow = mgrp*48 + mt*16 + hi*4;
                float4 bias = *(const float4*)(pwb + L*HIDDEN + mrow);
                unsigned short* ytW = g_u ? yt1 : yt0;
                #pragma unroll
                for (int nt = 0; nt < 3; ++nt) {
                    const int n = ngrp*48 + nt*16 + l15;
                    unsigned* zr = (unsigned*)(ytW + n*YS + mrow);
                    f32x4 v = acc[mt][nt];
                    zr[0] = packbf(v[0] + bias.x, v[1] + bias.y);
                    zr[1] = packbf(v[2] + bias.z, v[3] + bias.w);
                }
            }
        }
        __syncthreads();

        // ---- LN2 + GELU + residual (times mask) into hm (bf16) ----
        {
            const unsigned* gb = lnpp + (L*2+1)*HIDDEN;
            ln_pass(lnA_u ? yt1 : yt0, lnA_u ? hb1 : hb0, gb, lnA_u ? mk1 : mk0,
                    lnA_col, q8, jlo, jhi, false);
            if (slot < 64)
                ln_pass(yt1, hb1, gb, mk1, slot + 32, q8, jlo, jhi, false);
        }
        __syncthreads();
    }

    // ---- projection: p[o][j] = (proj_w @ hm + proj_b) * mask ----
    if constexpr (PREW) {
        const unsigned short* wpj = wbf + WPW_ELEMS;
        const int p_u = wu >> 3;
        const int p_mt = (wu >> 2) & 1;
        const int p_nt = wu & 3;
        unsigned short* hbU = p_u ? hb1 : hb0;
        float* pbU = (float*)(p_u ? yt1 : yt0);
        const float* mkU = p_u ? mk1 : mk0;
        const int j = p_nt*16 + l15;
        const int jj = HALO + j;
        f32x4 pacc = (f32x4){0.0f, 0.0f, 0.0f, 0.0f};
        #pragma unroll
        for (int ks = 0; ks < 6; ++ks) {
            bf16x8 a = *(const bf16x8*)(wpj + (size_t)(p_mt*16 + l15)*HIDDEN + ks*32 + hi*8);
            bf16x8 bb;
            #pragma unroll
            for (int e = 0; e < 8; ++e)
                bb[e] = (short)hbU[(ks*32 + hi*8 + e)*HS + jj];
            pacc = __builtin_amdgcn_mfma_f32_16x16x32_bf16(a, bb, pacc, 0, 0, 0);
        }
        const float mkv = mkU[jj];
        #pragma unroll
        for (int r = 0; r < 4; ++r) {
            const int o = p_mt*16 + hi*4 + r;
            if (o < PROJ)
                pbU[j*33 + o] = (pacc[r] + pjb[o]) * mkv;
        }
    } else {
        #pragma unroll
        for (int u = 0; u < 2; ++u) {
            unsigned short* hbU = u ? hb1 : hb0;
            float* pbU = (float*)(u ? yt1 : yt0);
            const float* mkU = u ? mk1 : mk0;
            const int j = lane;
            const int jj = HALO + j;
            const float mkv = mkU[jj];
            #pragma unroll
            for (int k = 0; k < 2; ++k) {
                const int o = wu + 16*k;
                if (o < PROJ) {
                    const float* w = pjw + (size_t)o*HIDDEN;
                    float acc = 0.0f;
                    #pragma unroll 4
                    for (int c = 0; c < HIDDEN; ++c)
                        acc = fmaf(w[c], bfs(hbU[c*HS + jj]), acc);
                    pbU[j*33 + o] = (acc + pjb[o]) * mkv;
                }
            }
        }
    }
    __syncthreads();

    // ---- spline epilogue: waves 0,1 -> tiles 0,1; scratch over hb ----
    float ladm = 0.0f;
    if (tid < 2*TT) {
        const int u = tid >> 6, j = tid & 63;
        float* pbU = (float*)(u ? yt1 : yt0);
        float* sc  = (float*)(u ? hb1 : hb0);
        const float* mkU = u ? mk1 : mk0;
        const int t = (tbb*2 + u)*TT + j;
        float* S  = sc + j*57;
        float* cw = S;          // 11
        float* ch = S + 11;     // 11
        float* wd = S + 22;     // 10
        float* ht = S + 32;     // 10
        float* dv = S + 42;     // 11

        const float x   = inputs[(size_t)b*2*NT + NT + t];
        const float fvv = inputs[(size_t)b*2*NT + t];
        const float mv  = mkU[HALO + j];

        {
            float uarr[NBINS]; float m = -1e30f;
            #pragma unroll
            for (int k = 0; k < NBINS; ++k) { uarr[k] = pbU[j*33 + k]*INV_SQRTF; m = fmaxf(m, uarr[k]); }
            float se = 0.0f;
            #pragma unroll
            for (int k = 0; k < NBINS; ++k) { uarr[k] = expf(uarr[k] - m); se += uarr[k]; }
            float inv = 1.0f/se, csum = 0.0f;
            cw[0] = -TAILF;
            #pragma unroll
            for (int k = 0; k < NBINS; ++k) {
                float wk = MIN_BIN + (1.0f - NBINS*MIN_BIN)*uarr[k]*inv;
                csum += wk;
                cw[k+1] = 2.0f*TAILF*csum - TAILF;
            }
            cw[NBINS] = TAILF;
            #pragma unroll
            for (int k = 0; k < NBINS; ++k) wd[k] = cw[k+1] - cw[k];
        }
        {
            float uarr[NBINS]; float m = -1e30f;
            #pragma unroll
            for (int k = 0; k < NBINS; ++k) { uarr[k] = pbU[j*33 + 10 + k]*INV_SQRTF; m = fmaxf(m, uarr[k]); }
            float se = 0.0f;
            #pragma unroll
            for (int k = 0; k < NBINS; ++k) { uarr[k] = expf(uarr[k] - m); se += uarr[k]; }
            float inv = 1.0f/se, csum = 0.0f;
            ch[0] = -TAILF;
            #pragma unroll
            for (int k = 0; k < NBINS; ++k) {
                float wk = MIN_BIN + (1.0f - NBINS*MIN_BIN)*uarr[k]*inv;
                csum += wk;
                ch[k+1] = 2.0f*TAILF*csum - TAILF;
            }
            ch[NBINS] = TAILF;
            #pragma unroll
            for (int k = 0; k < NBINS; ++k) ht[k] = ch[k+1] - ch[k];
        }
        {
            const float cpad = logf(expf(1.0f - MIN_DERF) - 1.0f);
            float edge = MIN_DERF + softplus_f(cpad);
            dv[0] = edge;
            #pragma unroll
            for (int k = 0; k < NBINS-1; ++k) dv[k+1] = MIN_DERF + softplus_f(pbU[j*33 + 2*NBINS + k]);
            dv[NBINS] = edge;
        }

        const float xi = fminf(fmaxf(x, -TAILF), TAILF);
        int cnt = 0;
        #pragma unroll
        for (int k = 0; k <= NBINS; ++k) {
            float bl = cw[k] + ((k == NBINS) ? 1e-6f : 0.0f);
            cnt += (xi >= bl) ? 1 : 0;
        }
        int bi = cnt - 1;
        bi = (bi < 0) ? 0 : ((bi > NBINS-1) ? NBINS-1 : bi);

        const float in_cw = cw[bi], in_w = wd[bi];
        const float in_ch = ch[bi], in_h = ht[bi];
        const float in_d  = ht[bi]/wd[bi];
        const float dA = dv[bi], dB = dv[bi+1];
        const float i1 = dA + dB - 2.0f*in_d;
        const float th = (xi - in_cw)/in_w;
        const float t1m = th*(1.0f - th);
        const float den = in_d + i1*t1m;
        const float outv = in_ch + in_h*(in_d*th*th + dA*t1m)/den;
        const float omt = 1.0f - th;
        const float dnum = in_d*in_d*(dB*th*th + 2.0f*in_d*t1m + dA*omt*omt);
        const float lad = logf(dnum) - 2.0f*logf(den);

        const bool inside = (x >= -TAILF) && (x <= TAILF);
        const float sec  = inside ? outv : x;
        ladm = (inside ? lad : 0.0f) * mv;

        out[(size_t)b*2*NT + t]      = fvv*mv;
        out[(size_t)b*2*NT + NT + t] = sec*mv;
    }
    if (tid < 128) {
        float tot = wave_sum(ladm);
        if (lane == 0) part[b*NTB + tbb*2 + (tid >> 6)] = tot;
    }
}

__global__ void ld_reduce(const float* __restrict__ part, float* __restrict__ ld) {
    int b = threadIdx.x;
    if (b < NB) {
        float s = 0.0f;
        for (int k = 0; k < NTB; ++k) s += part[b*NTB + k];
        ld[b] = s;
    }
}

extern "C" void kernel_launch(void* const* d_in, const int* in_sizes, int n_in,
                              void* d_out, int out_size, void* d_ws, size_t ws_size,
                              hipStream_t stream) {
    const float* inputs = (const float*)d_in[0];
    const float* pmask  = (const float*)d_in[1];
    const float* cpw    = (const float*)d_in[2];
    const float* cpb    = (const float*)d_in[3];
    const float* dww    = (const float*)d_in[4];
    const float* dwb    = (const float*)d_in[5];
    const float* pww    = (const float*)d_in[6];
    const float* pwb    = (const float*)d_in[7];
    const float* g1     = (const float*)d_in[8];
    const float* b1     = (const float*)d_in[9];
    const float* g2     = (const float*)d_in[10];
    const float* b2     = (const float*)d_in[11];
    const float* pjw    = (const float*)d_in[12];
    const float* pjb    = (const float*)d_in[13];
    float* out  = (float*)d_out;
    float* part = (float*)d_ws;

    const size_t need = WS_PART_BYTES + (size_t)WBF_TOTAL*2;
    const int preW = (ws_size >= need) ? 1 : 0;
    unsigned short* wbf = (unsigned short*)((char*)d_ws + WS_PART_BYTES);

    const size_t smem = (size_t)SMEM_FLOATS * sizeof(float);
    if (preW) {
        wconv_kernel<<<(WBF_TOTAL + 1023)/1024, 1024, 0, stream>>>(pww, pjw, wbf);
        hipFuncSetAttribute(reinterpret_cast<const void*>(&vits_fused<1>),
                            hipFuncAttributeMaxDynamicSharedMemorySize, (int)smem);
        vits_fused<1><<<NB*NBLK, THREADS, smem, stream>>>(inputs, pmask, cpw, cpb, dww, dwb,
                                                          pww, pwb, g1, b1, g2, b2, pjw, pjb,
                                                          out, part, wbf);
    } else {
        hipFuncSetAttribute(reinterpret_cast<const void*>(&vits_fused<0>),
                            hipFuncAttributeMaxDynamicSharedMemorySize, (int)smem);
        vits_fused<0><<<NB*NBLK, THREADS, smem, stream>>>(inputs, pmask, cpw, cpb, dww, dwb,
                                                          pww, pwb, g1, b1, g2, b2, pjw, pjb,
                                                          out, part, wbf);
    }
    ld_reduce<<<1, 64, 0, stream>>>(part, out + (size_t)NB*2*NT);
}